// Round 4
// baseline (316.852 us; speedup 1.0000x reference)
//
#include <hip/hip_runtime.h>

// AvgSeq: out[b,s,d] = (sum_{t<=s} x[b,t,d]) / (s+1)
// x: [16, 8192, 256] float32
//
// Single-pass chunked scan, AGGREGATE-ONLY windowed lookback:
//   - 4096 single-wave blocks, one per (b, chunk of 32 rows); lane = float4 col
//   - phase 1: chunk sum (16-deep load batches), publish aggregate + flag=1
//   - lookback: windows of 8 predecessors; lane-parallel flag poll (lanes 0-7),
//     then 16 independent aggregate loads per window (MLP), f64 accumulate.
//     No inclusive chain -> no serial publish->observe dependency at all.
//   - phase 2: rescan own chunk (L1/L2/L3-hot) and nontemporal-store means.
// Co-residency: VGPR <= 128 -> 16 waves/CU -> all 4096 blocks resident; blocks
// wait only on predecessors' phase-1 (independent work), so no deadlock.
#define BB 16
#define SS 8192
#define DD 256
#define D4 (DD / 4)       // 64 float4 columns = one wave
#define NC 256            // chunks along S
#define CL (SS / NC)      // 32 rows per chunk
#define G  16             // load-batch depth (16 KB in flight per wave)
#define W  8              // lookback window (flags polled + aggregates loaded together)

#define NBLK (BB * NC)                       // 4096
#define AGGA_OFF (64 * 1024)                 // flags occupy [0, 16KB)
#define AGG_BYTES (NBLK * DD * 4)            // 4 MiB aggregate table
#define WS_NEEDED ((size_t)(AGGA_OFF + AGG_BYTES))

typedef float nat4 __attribute__((ext_vector_type(4)));

union F2U { float2 f; unsigned long long u; };

__global__ __launch_bounds__(256) void avgseq_init(int* __restrict__ flags) {
    const int i = blockIdx.x * 256 + threadIdx.x;
    if (i < NBLK) flags[i] = 0;
}

__global__ __launch_bounds__(64, 4) void avgseq_lookback(
    const float4* __restrict__ x, float4* __restrict__ out,
    int* __restrict__ flags, unsigned long long* __restrict__ aggA)
{
    const int blk = blockIdx.x;          // b*NC + c
    const int b = blk >> 8;
    const int c = blk & (NC - 1);
    const int t = threadIdx.x;

    const size_t base = ((size_t)b * SS + (size_t)c * CL) * D4 + t;
    const float4* p = x + base;

    // ---- phase 1: chunk sum ----
    float4 agg = make_float4(0.f, 0.f, 0.f, 0.f);
    for (int s0 = 0; s0 < CL; s0 += G) {
        float4 v[G];
#pragma unroll
        for (int g = 0; g < G; ++g) v[g] = p[(size_t)(s0 + g) * D4];
#pragma unroll
        for (int g = 0; g < G; ++g) {
            agg.x += v[g].x; agg.y += v[g].y; agg.z += v[g].z; agg.w += v[g].w;
        }
    }

    // ---- publish aggregate (flag=1); last chunk of a batch has no reader ----
    if (c < NC - 1) {
        const size_t slot = (size_t)blk * (DD / 2) + (size_t)t * 2;
        F2U lo, hi;
        lo.f = make_float2(agg.x, agg.y);
        hi.f = make_float2(agg.z, agg.w);
        __hip_atomic_store(&aggA[slot],     lo.u, __ATOMIC_RELAXED, __HIP_MEMORY_SCOPE_AGENT);
        __hip_atomic_store(&aggA[slot + 1], hi.u, __ATOMIC_RELAXED, __HIP_MEMORY_SCOPE_AGENT);
        asm volatile("s_waitcnt vmcnt(0)" ::: "memory");  // HW release: data visible before flag
        __hip_atomic_store(&flags[blk], 1, __ATOMIC_RELAXED, __HIP_MEMORY_SCOPE_AGENT);
    }

    // ---- windowed lookback: sum aggregates of ALL preceding chunks (f64) ----
    double rx = 0.0, ry = 0.0, rz = 0.0, rw = 0.0;
    {
        const int fbase = b << 8;
        int cc = c - 1;
        while (cc >= 0) {
            const int w = (cc >= W - 1) ? W : (cc + 1);
            // lane-parallel flag poll: lane j (<w) watches flags[cc-j]
            int f = 1;
            if (t < w) f = __hip_atomic_load(&flags[fbase + cc - t],
                                             __ATOMIC_RELAXED, __HIP_MEMORY_SCOPE_AGENT);
            while (__ballot(f != 0) != ~0ULL) {
                __builtin_amdgcn_s_sleep(1);
                if (t < w) f = __hip_atomic_load(&flags[fbase + cc - t],
                                                 __ATOMIC_RELAXED, __HIP_MEMORY_SCOPE_AGENT);
            }
            // all w aggregates ready: issue 2*w independent loads, then accumulate
            unsigned long long a0[W], a1[W];
#pragma unroll
            for (int k = 0; k < W; ++k) {
                if (k < w) {
                    const size_t s2 = (size_t)(fbase + cc - k) * (DD / 2) + (size_t)t * 2;
                    a0[k] = __hip_atomic_load(&aggA[s2],     __ATOMIC_RELAXED, __HIP_MEMORY_SCOPE_AGENT);
                    a1[k] = __hip_atomic_load(&aggA[s2 + 1], __ATOMIC_RELAXED, __HIP_MEMORY_SCOPE_AGENT);
                }
            }
#pragma unroll
            for (int k = 0; k < W; ++k) {
                if (k < w) {
                    F2U a, bq; a.u = a0[k]; bq.u = a1[k];
                    rx += a.f.x; ry += a.f.y; rz += bq.f.x; rw += bq.f.y;
                }
            }
            cc -= w;
        }
    }
    float4 acc = make_float4((float)rx, (float)ry, (float)rz, (float)rw);

    // ---- phase 2: rescan own chunk (cache-hot) and emit means ----
    float4* o = out + base;
    const int sb = c * CL;
    for (int s0 = 0; s0 < CL; s0 += G) {
        float4 v[G];
#pragma unroll
        for (int g = 0; g < G; ++g) v[g] = p[(size_t)(s0 + g) * D4];
#pragma unroll
        for (int g = 0; g < G; ++g) {
            acc.x += v[g].x; acc.y += v[g].y; acc.z += v[g].z; acc.w += v[g].w;
            const float r = __builtin_amdgcn_rcpf((float)(sb + s0 + g + 1));
            v[g] = make_float4(acc.x * r, acc.y * r, acc.z * r, acc.w * r);
        }
#pragma unroll
        for (int g = 0; g < G; ++g) {
            nat4 nv = { v[g].x, v[g].y, v[g].z, v[g].w };
            __builtin_nontemporal_store(nv, (nat4*)&o[(size_t)(s0 + g) * D4]);  // out never re-read
        }
    }
}

// ---------------- fallback (verified round-1 path) if ws is too small ----------------
__global__ __launch_bounds__(64) void avgseq_chunksum(const float4* __restrict__ x,
                                                      float4* __restrict__ ws) {
    const int blk = blockIdx.x;
    const int b = blk >> 8;
    const int c = blk & (NC - 1);
    const int t = threadIdx.x;
    const float4* p = x + ((size_t)b * SS + (size_t)c * CL) * D4 + t;
    float4 acc = make_float4(0.f, 0.f, 0.f, 0.f);
    for (int s0 = 0; s0 < CL; s0 += G) {
        float4 v[G];
#pragma unroll
        for (int g = 0; g < G; ++g) v[g] = p[(size_t)(s0 + g) * D4];
#pragma unroll
        for (int g = 0; g < G; ++g) {
            acc.x += v[g].x; acc.y += v[g].y; acc.z += v[g].z; acc.w += v[g].w;
        }
    }
    ws[((size_t)b * NC + c) * D4 + t] = acc;
}

__global__ __launch_bounds__(64) void avgseq_scanws(float4* __restrict__ ws) {
    const int b = blockIdx.x;
    const int t = threadIdx.x;
    float4* w = ws + (size_t)b * NC * D4 + t;
    float4 run = make_float4(0.f, 0.f, 0.f, 0.f);
#pragma unroll 8
    for (int c = 0; c < NC; ++c) {
        float4 v = w[(size_t)c * D4];
        w[(size_t)c * D4] = run;
        run.x += v.x; run.y += v.y; run.z += v.z; run.w += v.w;
    }
}

__global__ __launch_bounds__(64) void avgseq_scan(const float4* __restrict__ x,
                                                  const float4* __restrict__ ws,
                                                  float4* __restrict__ out) {
    const int blk = blockIdx.x;
    const int b = blk >> 8;
    const int c = blk & (NC - 1);
    const int t = threadIdx.x;
    float4 acc = ws[((size_t)b * NC + c) * D4 + t];
    const size_t base = ((size_t)b * SS + (size_t)c * CL) * D4 + t;
    const float4* p = x + base;
    float4* o = out + base;
    const int s0 = c * CL;
    for (int ss = 0; ss < CL; ss += G) {
        float4 v[G];
#pragma unroll
        for (int g = 0; g < G; ++g) v[g] = p[(size_t)(ss + g) * D4];
#pragma unroll
        for (int g = 0; g < G; ++g) {
            acc.x += v[g].x; acc.y += v[g].y; acc.z += v[g].z; acc.w += v[g].w;
            const float r = __builtin_amdgcn_rcpf((float)(s0 + ss + g + 1));
            v[g] = make_float4(acc.x * r, acc.y * r, acc.z * r, acc.w * r);
        }
#pragma unroll
        for (int g = 0; g < G; ++g) o[(size_t)(ss + g) * D4] = v[g];
    }
}

extern "C" void kernel_launch(void* const* d_in, const int* in_sizes, int n_in,
                              void* d_out, int out_size, void* d_ws, size_t ws_size,
                              hipStream_t stream) {
    const float4* x = (const float4*)d_in[0];
    float4* out = (float4*)d_out;

    if (ws_size >= WS_NEEDED) {
        int* flags = (int*)d_ws;
        unsigned long long* aggA = (unsigned long long*)((char*)d_ws + AGGA_OFF);
        avgseq_init<<<(NBLK + 255) / 256, 256, 0, stream>>>(flags);
        avgseq_lookback<<<NBLK, 64, 0, stream>>>(x, out, flags, aggA);
    } else {
        float4* ws = (float4*)d_ws;
        avgseq_chunksum<<<NBLK, 64, 0, stream>>>(x, ws);
        avgseq_scanws<<<BB, 64, 0, stream>>>(ws);
        avgseq_scan<<<NBLK, 64, 0, stream>>>(x, ws, out);
    }
}

// Round 5
// 251.375 us; speedup vs baseline: 1.2605x; 1.2605x over previous
//
#include <hip/hip_runtime.h>

// AvgSeq: out[b,s,d] = (sum_{t<=s} x[b,t,d]) / (s+1)
// x: [16, 8192, 256] float32
//
// Two-pass chunked scan (measured-best structure, R0), upgraded K2:
//   K1: chunk sums -> ws       (one wave per (b,chunk), lane = float4 column)
//   K2: prefix over preceding chunk sums (8-deep MLP windows, L2-resident),
//       then software-pipelined scan of own chunk: 2 named 16-wide load
//       batches in flight (32 KB/wave), nontemporal stores (out never re-read).
#define BB 16
#define SS 8192
#define DD 256
#define D4 (DD / 4)     // 64 float4 columns; one wave covers all of D
#define NC 128          // chunks along S
#define CL (SS / NC)    // 64 rows per chunk
#define G  16           // load-batch width (16 KB per batch per wave)

typedef float nat4 __attribute__((ext_vector_type(4)));

__global__ __launch_bounds__(64) void avgseq_chunksum(const float4* __restrict__ x,
                                                      float4* __restrict__ ws) {
    const int blk = blockIdx.x;          // b*NC + c
    const int b = blk >> 7;              // / NC
    const int c = blk & (NC - 1);
    const int t = threadIdx.x;           // float4 column

    const float4* p = x + ((size_t)b * SS + (size_t)c * CL) * D4 + t;
    float4 acc = make_float4(0.f, 0.f, 0.f, 0.f);
    for (int s0 = 0; s0 < CL; s0 += G) {
        float4 v[G];
#pragma unroll
        for (int g = 0; g < G; ++g) v[g] = p[(size_t)(s0 + g) * D4];
#pragma unroll
        for (int g = 0; g < G; ++g) {
            acc.x += v[g].x; acc.y += v[g].y; acc.z += v[g].z; acc.w += v[g].w;
        }
    }
    ws[((size_t)b * NC + c) * D4 + t] = acc;
}

__global__ __launch_bounds__(64) void avgseq_scan(const float4* __restrict__ x,
                                                  const float4* __restrict__ ws,
                                                  float4* __restrict__ out) {
    const int blk = blockIdx.x;          // b*NC + c
    const int b = blk >> 7;
    const int c = blk & (NC - 1);
    const int t = threadIdx.x;

    // ---- prefix over chunk sums < c: 8-deep MLP windows (table is L2-resident) ----
    const float4* w = ws + (size_t)b * NC * D4 + t;
    float4 pre = make_float4(0.f, 0.f, 0.f, 0.f);
    int cc = 0;
    for (; cc + 8 <= c; cc += 8) {
        float4 a[8];
#pragma unroll
        for (int k = 0; k < 8; ++k) a[k] = w[(size_t)(cc + k) * D4];
#pragma unroll
        for (int k = 0; k < 8; ++k) {
            pre.x += a[k].x; pre.y += a[k].y; pre.z += a[k].z; pre.w += a[k].w;
        }
    }
    for (; cc < c; ++cc) {
        float4 v = w[(size_t)cc * D4];
        pre.x += v.x; pre.y += v.y; pre.z += v.z; pre.w += v.w;
    }

    const size_t base = ((size_t)b * SS + (size_t)c * CL) * D4 + t;
    const float4* p = x + base;
    float4* o = out + base;
    const int s0 = c * CL;
    float4 acc = pre;

    // ---- software-pipelined main scan: CL=64 rows = 4 named batches of G=16 ----
    float4 v0[G], v1[G];
#define LOADB(dst, off)                                                        \
    _Pragma("unroll")                                                          \
    for (int g = 0; g < G; ++g) dst[g] = p[(size_t)((off) + g) * D4];
#define COMPSTORE(src, off)                                                    \
    _Pragma("unroll")                                                          \
    for (int g = 0; g < G; ++g) {                                              \
        acc.x += src[g].x; acc.y += src[g].y;                                  \
        acc.z += src[g].z; acc.w += src[g].w;                                  \
        const float r = __builtin_amdgcn_rcpf((float)(s0 + (off) + g + 1));    \
        nat4 nv = { acc.x * r, acc.y * r, acc.z * r, acc.w * r };              \
        __builtin_nontemporal_store(nv, (nat4*)&o[(size_t)((off) + g) * D4]);  \
    }

    LOADB(v0, 0)
    LOADB(v1, G)            // 32 loads (32 KB) in flight
    COMPSTORE(v0, 0)        // waits only on first 16 loads
    LOADB(v0, 2 * G)
    COMPSTORE(v1, G)
    LOADB(v1, 3 * G)
    COMPSTORE(v0, 2 * G)
    COMPSTORE(v1, 3 * G)
#undef LOADB
#undef COMPSTORE
}

extern "C" void kernel_launch(void* const* d_in, const int* in_sizes, int n_in,
                              void* d_out, int out_size, void* d_ws, size_t ws_size,
                              hipStream_t stream) {
    const float4* x = (const float4*)d_in[0];
    float4* out = (float4*)d_out;
    float4* ws = (float4*)d_ws;          // BB*NC*D4 float4 = 2 MiB

    const int nblocks = BB * NC;         // 2048 single-wave blocks = 8 waves/CU
    avgseq_chunksum<<<nblocks, 64, 0, stream>>>(x, ws);
    avgseq_scan<<<nblocks, 64, 0, stream>>>(x, ws, out);
}